// Round 1
// baseline (744.664 us; speedup 1.0000x reference)
//
#include <hip/hip_runtime.h>
#include <hip/hip_bf16.h>

#define HEADS 3
#define HID 128
#define FDIM (HEADS * HID)   // 384

__device__ __forceinline__ float lrelu(float x) { return x >= 0.f ? x : 0.2f * x; }
__device__ __forceinline__ float rrelu(float x) {
    const float SLOPE = (1.0f / 8.0f + 1.0f / 3.0f) * 0.5f;
    return x >= 0.f ? x : SLOPE * x;
}

// ---------------- CSR build (counting sort by dst) ----------------

__global__ void k_hist(const int* __restrict__ dst, int E, int* __restrict__ cnt) {
    for (int i = blockIdx.x * blockDim.x + threadIdx.x; i < E; i += gridDim.x * blockDim.x)
        atomicAdd(&cnt[dst[i]], 1);
}

__global__ __launch_bounds__(1024) void k_scan(const int* __restrict__ cnt,
                                               int* __restrict__ offs, int n) {
    __shared__ int sm[1024];
    __shared__ int running_s;
    int tid = threadIdx.x;
    if (tid == 0) running_s = 0;
    __syncthreads();
    for (int base = 0; base < n; base += 1024) {
        int i = base + tid;
        int v = (i < n) ? cnt[i] : 0;
        sm[tid] = v;
        __syncthreads();
        for (int off = 1; off < 1024; off <<= 1) {
            int t = (tid >= off) ? sm[tid - off] : 0;
            __syncthreads();
            sm[tid] += t;
            __syncthreads();
        }
        int r0 = running_s;         // safe: last write was before a barrier
        int excl = sm[tid] - v;
        if (i < n) offs[i] = r0 + excl;
        int tot = sm[1023];
        __syncthreads();
        if (tid == 0) running_s += tot;
        __syncthreads();
    }
    if (tid == 0) offs[n] = running_s;
}

__global__ void k_copy(const int* __restrict__ a, int* __restrict__ b, int n) {
    for (int i = blockIdx.x * blockDim.x + threadIdx.x; i < n; i += gridDim.x * blockDim.x)
        b[i] = a[i];
}

__global__ void k_scatter(const int* __restrict__ src, const int* __restrict__ dst, int E,
                          int* __restrict__ cursor, int* __restrict__ ssrc) {
    for (int i = blockIdx.x * blockDim.x + threadIdx.x; i < E; i += gridDim.x * blockDim.x) {
        int d = dst[i];
        int p = atomicAdd(&cursor[d], 1);
        ssrc[p] = src[i];
    }
}

// ---------------- fp32 tiled GEMM:  C[M,Ncols] = A[M,K] @ W[K,Ncols] ----------------
// A is logically concat(A0, A1) along K at `split` (A1 may be null when split==K).

#define BM 64
#define BN 64
#define BKK 16

__global__ __launch_bounds__(256) void k_gemm(const float* __restrict__ A0,
                                              const float* __restrict__ A1, int split,
                                              const float* __restrict__ W,
                                              float* __restrict__ C,
                                              int M, int K, int Ncols) {
    __shared__ float As[BKK][BM + 1];
    __shared__ float Bs[BKK][BN + 1];
    int tid  = threadIdx.x;
    int trow = tid / 16;
    int tcol = tid % 16;
    int row0 = blockIdx.x * BM;
    int col0 = blockIdx.y * BN;
    float acc[4][4] = {};

    int ar  = tid / 4;            // 0..63
    int ak0 = (tid % 4) * 4;      // 0,4,8,12
    int bk  = tid / 16;           // 0..15
    int bj0 = (tid % 16) * 4;

    int grow = row0 + ar;
    bool rvalid = grow < M;
    const float* Arow0 = A0 + (size_t)grow * (size_t)split;
    const float* Arow1 = A1 ? (A1 + (size_t)grow * (size_t)(K - split)) : nullptr;

    for (int k0 = 0; k0 < K; k0 += BKK) {
#pragma unroll
        for (int i = 0; i < 4; i++) {
            int k = k0 + ak0 + i;
            float v = 0.f;
            if (rvalid) v = (k < split) ? Arow0[k] : Arow1[k - split];
            As[ak0 + i][ar] = v;
        }
#pragma unroll
        for (int i = 0; i < 4; i++)
            Bs[bk][bj0 + i] = W[(size_t)(k0 + bk) * Ncols + col0 + bj0 + i];
        __syncthreads();
#pragma unroll
        for (int kk = 0; kk < BKK; kk++) {
            float a[4], b[4];
#pragma unroll
            for (int i = 0; i < 4; i++) a[i] = As[kk][trow * 4 + i];
#pragma unroll
            for (int j = 0; j < 4; j++) b[j] = Bs[kk][tcol * 4 + j];
#pragma unroll
            for (int i = 0; i < 4; i++)
#pragma unroll
                for (int j = 0; j < 4; j++) acc[i][j] = fmaf(a[i], b[j], acc[i][j]);
        }
        __syncthreads();
    }
#pragma unroll
    for (int i = 0; i < 4; i++) {
        int r = row0 + trow * 4 + i;
        if (r < M) {
#pragma unroll
            for (int j = 0; j < 4; j++)
                C[(size_t)r * Ncols + col0 + tcol * 4 + j] = acc[i][j];
        }
    }
}

// ---------------- per-node attention logits: es/ed [N,3] ----------------

__global__ __launch_bounds__(128) void k_edge_logits(const float* __restrict__ H,
                                                     const float* __restrict__ asrc,
                                                     const float* __restrict__ adst,
                                                     float* __restrict__ es,
                                                     float* __restrict__ ed, int Nn) {
    int n = blockIdx.x;
    int t = threadIdx.x;
    int lane = t & 63, wv = t >> 6;
    __shared__ float red[2][HEADS][2];
#pragma unroll
    for (int h = 0; h < HEADS; h++) {
        float v  = H[(size_t)n * FDIM + h * HID + t];
        float ps = v * asrc[h * HID + t];
        float pd = v * adst[h * HID + t];
#pragma unroll
        for (int off = 32; off > 0; off >>= 1) {
            ps += __shfl_down(ps, off);
            pd += __shfl_down(pd, off);
        }
        if (lane == 0) { red[wv][h][0] = ps; red[wv][h][1] = pd; }
    }
    __syncthreads();
    if (t < HEADS) {
        es[n * HEADS + t] = red[0][t][0] + red[1][t][0];
        ed[n * HEADS + t] = red[0][t][1] + red[1][t][1];
    }
}

// ---------------- GAT aggregate, layer 1 (mean over heads + bias + rrelu) ----------------

__global__ __launch_bounds__(128) void k_gat_mean(const float* __restrict__ H,
                                                  const float* __restrict__ es,
                                                  const float* __restrict__ ed,
                                                  const int* __restrict__ offs,
                                                  const int* __restrict__ ssrc,
                                                  const float* __restrict__ b,
                                                  float* __restrict__ out, int Nn) {
    int n = blockIdx.x;
    int c = threadIdx.x;
    float ed0 = ed[n * 3 + 0], ed1 = ed[n * 3 + 1], ed2 = ed[n * 3 + 2];
    float acc0 = 0, acc1 = 0, acc2 = 0, den0 = 0, den1 = 0, den2 = 0;
    int j0 = offs[n], j1 = offs[n + 1];
    for (int j = j0 - 1; j < j1; j++) {          // j0-1 == self loop
        int s = (j < j0) ? n : ssrc[j];
        float w0 = __expf(lrelu(es[s * 3 + 0] + ed0));
        float w1 = __expf(lrelu(es[s * 3 + 1] + ed1));
        float w2 = __expf(lrelu(es[s * 3 + 2] + ed2));
        const float* hp = H + (size_t)s * FDIM + c;
        acc0 = fmaf(w0, hp[0], acc0);
        acc1 = fmaf(w1, hp[HID], acc1);
        acc2 = fmaf(w2, hp[2 * HID], acc2);
        den0 += w0; den1 += w1; den2 += w2;
    }
    float m = (acc0 / den0 + acc1 / den1 + acc2 / den2) * (1.f / 3.f) + b[c];
    out[(size_t)n * HID + c] = rrelu(m);
}

// ---------------- GAT aggregate, layer 2 (concat + bias + rrelu) fused with linear+sigmoid ----------------

__global__ __launch_bounds__(128) void k_gat_cat_final(const float* __restrict__ H,
                                                       const float* __restrict__ es,
                                                       const float* __restrict__ ed,
                                                       const int* __restrict__ offs,
                                                       const int* __restrict__ ssrc,
                                                       const float* __restrict__ b,
                                                       const float* __restrict__ Wl,
                                                       const float* __restrict__ bl,
                                                       float* __restrict__ out, int Nn) {
    int n = blockIdx.x;
    int c = threadIdx.x;
    float ed0 = ed[n * 3 + 0], ed1 = ed[n * 3 + 1], ed2 = ed[n * 3 + 2];
    float acc0 = 0, acc1 = 0, acc2 = 0, den0 = 0, den1 = 0, den2 = 0;
    int j0 = offs[n], j1 = offs[n + 1];
    for (int j = j0 - 1; j < j1; j++) {
        int s = (j < j0) ? n : ssrc[j];
        float w0 = __expf(lrelu(es[s * 3 + 0] + ed0));
        float w1 = __expf(lrelu(es[s * 3 + 1] + ed1));
        float w2 = __expf(lrelu(es[s * 3 + 2] + ed2));
        const float* hp = H + (size_t)s * FDIM + c;
        acc0 = fmaf(w0, hp[0], acc0);
        acc1 = fmaf(w1, hp[HID], acc1);
        acc2 = fmaf(w2, hp[2 * HID], acc2);
        den0 += w0; den1 += w1; den2 += w2;
    }
    float r0 = rrelu(acc0 / den0 + b[c]);
    float r1 = rrelu(acc1 / den1 + b[HID + c]);
    float r2 = rrelu(acc2 / den2 + b[2 * HID + c]);
    float p = r0 * Wl[c] + r1 * Wl[HID + c] + r2 * Wl[2 * HID + c];
    int lane = c & 63, wv = c >> 6;
#pragma unroll
    for (int off = 32; off > 0; off >>= 1) p += __shfl_down(p, off);
    __shared__ float red[2];
    if (lane == 0) red[wv] = p;
    __syncthreads();
    if (c == 0) out[n] = 1.f / (1.f + __expf(-(red[0] + red[1] + bl[0])));
}

// ---------------- launch ----------------

extern "C" void kernel_launch(void* const* d_in, const int* in_sizes, int n_in,
                              void* d_out, int out_size, void* d_ws, size_t ws_size,
                              hipStream_t stream) {
    const float* z   = (const float*)d_in[0];
    const float* x   = (const float*)d_in[1];
    const int*   ei  = (const int*)d_in[2];
    const float* W1  = (const float*)d_in[3];
    const float* a1s = (const float*)d_in[4];
    const float* a1d = (const float*)d_in[5];
    const float* b1  = (const float*)d_in[6];
    const float* W2  = (const float*)d_in[7];
    const float* a2s = (const float*)d_in[8];
    const float* a2d = (const float*)d_in[9];
    const float* b2  = (const float*)d_in[10];
    const float* Wl  = (const float*)d_in[11];
    const float* bl  = (const float*)d_in[12];
    float* outp = (float*)d_out;

    int Nn = in_sizes[0] / 128;      // EMB = 128
    int E  = in_sizes[2] / 2;

    char* p = (char*)d_ws;
    auto carve = [&](size_t bytes) -> char* {
        char* r = p;
        p += (bytes + 255) & ~(size_t)255;
        return r;
    };
    int*   offs   = (int*)carve((size_t)(Nn + 1) * 4);
    int*   cursor = (int*)carve((size_t)Nn * 4);
    int*   ssrc   = (int*)carve((size_t)E * 4);
    float* e1s    = (float*)carve((size_t)Nn * 3 * 4);
    float* e1d    = (float*)carve((size_t)Nn * 3 * 4);
    float* Hbig   = (float*)carve((size_t)Nn * FDIM * 4);  // H1raw, then H2raw
    float* H2in   = (float*)carve((size_t)Nn * HID * 4);

    const int* srcI = ei;
    const int* dstI = ei + E;

    // CSR build
    hipMemsetAsync(cursor, 0, (size_t)Nn * 4, stream);
    k_hist<<<256, 256, 0, stream>>>(dstI, E, cursor);
    k_scan<<<1, 1024, 0, stream>>>(cursor, offs, Nn);
    k_copy<<<256, 256, 0, stream>>>(offs, cursor, Nn);
    k_scatter<<<256, 256, 0, stream>>>(srcI, dstI, E, cursor, ssrc);

    dim3 g1((Nn + BM - 1) / BM, FDIM / BN);

    // Layer 1
    k_gemm<<<g1, 256, 0, stream>>>(z, x, 128, W1, Hbig, Nn, 256, FDIM);
    k_edge_logits<<<Nn, 128, 0, stream>>>(Hbig, a1s, a1d, e1s, e1d, Nn);
    k_gat_mean<<<Nn, 128, 0, stream>>>(Hbig, e1s, e1d, offs, ssrc, b1, H2in, Nn);

    // Layer 2 (+ fused linear + sigmoid)
    k_gemm<<<g1, 256, 0, stream>>>(H2in, nullptr, 128, W2, Hbig, Nn, 128, FDIM);
    k_edge_logits<<<Nn, 128, 0, stream>>>(Hbig, a2s, a2d, e1s, e1d, Nn);
    k_gat_cat_final<<<Nn, 128, 0, stream>>>(Hbig, e1s, e1d, offs, ssrc, b2, Wl, bl, outp, Nn);
}

// Round 2
// 435.001 us; speedup vs baseline: 1.7119x; 1.7119x over previous
//
#include <hip/hip_runtime.h>
#include <stdint.h>

#define HEADS 3
#define HID 128
#define FDIM (HEADS * HID)   // 384

typedef __attribute__((ext_vector_type(8))) short bf16x8;
typedef __attribute__((ext_vector_type(4))) float f32x4;

__device__ __forceinline__ float lrelu(float x) { return x >= 0.f ? x : 0.2f * x; }
__device__ __forceinline__ float rrelu(float x) {
    const float SLOPE = (1.0f / 8.0f + 1.0f / 3.0f) * 0.5f;
    return x >= 0.f ? x : SLOPE * x;
}
__device__ __forceinline__ unsigned short f2bf(float f) {
    union { float f; unsigned u; } c; c.f = f;
    unsigned r = c.u + 0x7FFF + ((c.u >> 16) & 1);   // RNE
    return (unsigned short)(r >> 16);
}
__device__ __forceinline__ float bf2f(unsigned short b) {
    union { unsigned u; float f; } c; c.u = (unsigned)b << 16;
    return c.f;
}

__device__ __forceinline__ void gload_lds16(const void* g, void* l) {
    __builtin_amdgcn_global_load_lds(
        (const __attribute__((address_space(1))) void*)g,
        (__attribute__((address_space(3))) void*)l, 16, 0, 0);
}

// ---------------- CSR build (counting sort by dst) ----------------

__global__ void k_hist(const int* __restrict__ dst, int E, int* __restrict__ cnt) {
    for (int i = blockIdx.x * blockDim.x + threadIdx.x; i < E; i += gridDim.x * blockDim.x)
        atomicAdd(&cnt[dst[i]], 1);
}

__global__ __launch_bounds__(1024) void k_scan(const int* __restrict__ cnt,
                                               int* __restrict__ offs, int n) {
    __shared__ int sm[1024];
    __shared__ int running_s;
    int tid = threadIdx.x;
    if (tid == 0) running_s = 0;
    __syncthreads();
    for (int base = 0; base < n; base += 1024) {
        int i = base + tid;
        int v = (i < n) ? cnt[i] : 0;
        sm[tid] = v;
        __syncthreads();
        for (int off = 1; off < 1024; off <<= 1) {
            int t = (tid >= off) ? sm[tid - off] : 0;
            __syncthreads();
            sm[tid] += t;
            __syncthreads();
        }
        int r0 = running_s;
        int excl = sm[tid] - v;
        if (i < n) offs[i] = r0 + excl;
        int tot = sm[1023];
        __syncthreads();
        if (tid == 0) running_s += tot;
        __syncthreads();
    }
    if (tid == 0) offs[n] = running_s;
}

__global__ void k_copy(const int* __restrict__ a, int* __restrict__ b, int n) {
    for (int i = blockIdx.x * blockDim.x + threadIdx.x; i < n; i += gridDim.x * blockDim.x)
        b[i] = a[i];
}

__global__ void k_scatter(const int* __restrict__ src, const int* __restrict__ dst, int E,
                          int* __restrict__ cursor, int* __restrict__ ssrc) {
    for (int i = blockIdx.x * blockDim.x + threadIdx.x; i < E; i += gridDim.x * blockDim.x) {
        int d = dst[i];
        int p = atomicAdd(&cursor[d], 1);
        ssrc[p] = src[i];
    }
}

// ---------------- bf16 converts ----------------

// A[Mpad][256] = bf16(concat(z,x)); pad rows zeroed.
__global__ void k_cvt_concat(const float* __restrict__ z, const float* __restrict__ x,
                             unsigned short* __restrict__ A, int Nn, int Mpad) {
    int total = Mpad * 64;                       // 4 elems / thread
    for (int i = blockIdx.x * blockDim.x + threadIdx.x; i < total;
         i += gridDim.x * blockDim.x) {
        int row = i >> 6;
        int c4 = (i & 63) * 4;
        float4 v = make_float4(0.f, 0.f, 0.f, 0.f);
        if (row < Nn) {
            const float* sp = (c4 < 128) ? (z + (size_t)row * 128 + c4)
                                         : (x + (size_t)row * 128 + (c4 - 128));
            v = *(const float4*)sp;
        }
        unsigned short o[4] = {f2bf(v.x), f2bf(v.y), f2bf(v.z), f2bf(v.w)};
        *(uint2*)&A[(size_t)row * 256 + c4] = *(uint2*)o;
    }
}

// WT[Ncols][K] = bf16(W[K][Ncols]^T)
__global__ void k_cvt_wt(const float* __restrict__ W, unsigned short* __restrict__ WT,
                         int K, int Ncols) {
    int n = blockIdx.x;
    for (int k = threadIdx.x; k < K; k += blockDim.x)
        WT[(size_t)n * K + k] = f2bf(W[(size_t)k * Ncols + n]);
}

// ---------------- bf16 MFMA GEMM: C[Mpad,Ncols] = A[Mpad,K] @ BT[Ncols,K]^T ----------------
// 128x128 tile, BK=32, 4 waves, 16x16x32 MFMA, global_load_lds staging.

__global__ __launch_bounds__(256) void k_gemm_bf16(
    const unsigned short* __restrict__ A,
    const unsigned short* __restrict__ BT,
    unsigned short* __restrict__ C,
    int K, int Ncols) {
    __shared__ __align__(16) unsigned short As[128 * 32];
    __shared__ __align__(16) unsigned short Bs[128 * 32];
    int tid = threadIdx.x;
    int w = tid >> 6, lane = tid & 63;
    int row0 = blockIdx.x * 128;
    int col0 = blockIdx.y * 128;
    int wr = w >> 1, wc = w & 1;            // wave's 64x64 subtile

    f32x4 acc[4][4] = {};
    int frow = lane & 15;
    int fk = (lane >> 4) * 8;

    for (int k0 = 0; k0 < K; k0 += 32) {
#pragma unroll
        for (int i = 0; i < 2; i++) {
            int c = (i * 4 + w) * 64 + lane;        // chunk: row c>>2, 8 elems at (c&3)*8
            gload_lds16(A + (size_t)(row0 + (c >> 2)) * K + k0 + (c & 3) * 8,
                        (char*)As + (i * 4 + w) * 1024);
        }
#pragma unroll
        for (int i = 0; i < 2; i++) {
            int c = (i * 4 + w) * 64 + lane;
            gload_lds16(BT + (size_t)(col0 + (c >> 2)) * K + k0 + (c & 3) * 8,
                        (char*)Bs + (i * 4 + w) * 1024);
        }
        asm volatile("s_waitcnt vmcnt(0)" ::: "memory");
        __syncthreads();

        bf16x8 af[4], bfr[4];
#pragma unroll
        for (int m = 0; m < 4; m++)
            af[m] = *(const bf16x8*)&As[(wr * 64 + m * 16 + frow) * 32 + fk];
#pragma unroll
        for (int n = 0; n < 4; n++)
            bfr[n] = *(const bf16x8*)&Bs[(wc * 64 + n * 16 + frow) * 32 + fk];
#pragma unroll
        for (int m = 0; m < 4; m++)
#pragma unroll
            for (int n = 0; n < 4; n++)
                acc[m][n] = __builtin_amdgcn_mfma_f32_16x16x32_bf16(af[m], bfr[n], acc[m][n], 0, 0, 0);
        __syncthreads();
    }

    // C/D: col = lane&15, row = (lane>>4)*4 + j  [m89-verified]
    int ccol = lane & 15, crow = (lane >> 4) * 4;
#pragma unroll
    for (int m = 0; m < 4; m++)
#pragma unroll
        for (int n = 0; n < 4; n++)
#pragma unroll
            for (int j = 0; j < 4; j++) {
                int r = row0 + wr * 64 + m * 16 + crow + j;
                int cc = col0 + wc * 64 + n * 16 + ccol;
                C[(size_t)r * Ncols + cc] = f2bf(acc[m][n][j]);
            }
}

// ---------------- per-node attention logits: es/ed [N,3] ----------------

__global__ __launch_bounds__(128) void k_edge_logits(const unsigned short* __restrict__ H,
                                                     const float* __restrict__ asrc,
                                                     const float* __restrict__ adst,
                                                     float* __restrict__ es,
                                                     float* __restrict__ ed, int Nn) {
    int n = blockIdx.x;
    int t = threadIdx.x;
    int lane = t & 63, wv = t >> 6;
    __shared__ float red[2][HEADS][2];
#pragma unroll
    for (int h = 0; h < HEADS; h++) {
        float v = bf2f(H[(size_t)n * FDIM + h * HID + t]);
        float ps = v * asrc[h * HID + t];
        float pd = v * adst[h * HID + t];
#pragma unroll
        for (int off = 32; off > 0; off >>= 1) {
            ps += __shfl_down(ps, off);
            pd += __shfl_down(pd, off);
        }
        if (lane == 0) { red[wv][h][0] = ps; red[wv][h][1] = pd; }
    }
    __syncthreads();
    if (t < HEADS) {
        es[n * HEADS + t] = red[0][t][0] + red[1][t][0];
        ed[n * HEADS + t] = red[0][t][1] + red[1][t][1];
    }
}

// ---------------- GAT aggregate, layer 1 (mean heads + bias + rrelu) -> bf16 ----------------

__global__ __launch_bounds__(128) void k_gat_mean(const unsigned short* __restrict__ H,
                                                  const float* __restrict__ es,
                                                  const float* __restrict__ ed,
                                                  const int* __restrict__ offs,
                                                  const int* __restrict__ ssrc,
                                                  const float* __restrict__ b,
                                                  unsigned short* __restrict__ out, int Nn) {
    int n = blockIdx.x;
    int c = threadIdx.x;
    float ed0 = ed[n * 3 + 0], ed1 = ed[n * 3 + 1], ed2 = ed[n * 3 + 2];
    float acc0 = 0, acc1 = 0, acc2 = 0, den0 = 0, den1 = 0, den2 = 0;
    int j0 = offs[n], j1 = offs[n + 1];
    for (int j = j0 - 1; j < j1; j++) {          // j0-1 == self loop
        int s = (j < j0) ? n : ssrc[j];
        float w0 = __expf(lrelu(es[s * 3 + 0] + ed0));
        float w1 = __expf(lrelu(es[s * 3 + 1] + ed1));
        float w2 = __expf(lrelu(es[s * 3 + 2] + ed2));
        const unsigned short* hp = H + (size_t)s * FDIM + c;
        acc0 = fmaf(w0, bf2f(hp[0]), acc0);
        acc1 = fmaf(w1, bf2f(hp[HID]), acc1);
        acc2 = fmaf(w2, bf2f(hp[2 * HID]), acc2);
        den0 += w0; den1 += w1; den2 += w2;
    }
    float m = (acc0 / den0 + acc1 / den1 + acc2 / den2) * (1.f / 3.f) + b[c];
    out[(size_t)n * HID + c] = f2bf(rrelu(m));
}

// ---------------- GAT aggregate, layer 2 (concat) fused with linear+sigmoid ----------------

__global__ __launch_bounds__(128) void k_gat_cat_final(const unsigned short* __restrict__ H,
                                                       const float* __restrict__ es,
                                                       const float* __restrict__ ed,
                                                       const int* __restrict__ offs,
                                                       const int* __restrict__ ssrc,
                                                       const float* __restrict__ b,
                                                       const float* __restrict__ Wl,
                                                       const float* __restrict__ bl,
                                                       float* __restrict__ out, int Nn) {
    int n = blockIdx.x;
    int c = threadIdx.x;
    float ed0 = ed[n * 3 + 0], ed1 = ed[n * 3 + 1], ed2 = ed[n * 3 + 2];
    float acc0 = 0, acc1 = 0, acc2 = 0, den0 = 0, den1 = 0, den2 = 0;
    int j0 = offs[n], j1 = offs[n + 1];
    for (int j = j0 - 1; j < j1; j++) {
        int s = (j < j0) ? n : ssrc[j];
        float w0 = __expf(lrelu(es[s * 3 + 0] + ed0));
        float w1 = __expf(lrelu(es[s * 3 + 1] + ed1));
        float w2 = __expf(lrelu(es[s * 3 + 2] + ed2));
        const unsigned short* hp = H + (size_t)s * FDIM + c;
        acc0 = fmaf(w0, bf2f(hp[0]), acc0);
        acc1 = fmaf(w1, bf2f(hp[HID]), acc1);
        acc2 = fmaf(w2, bf2f(hp[2 * HID]), acc2);
        den0 += w0; den1 += w1; den2 += w2;
    }
    float r0 = rrelu(acc0 / den0 + b[c]);
    float r1 = rrelu(acc1 / den1 + b[HID + c]);
    float r2 = rrelu(acc2 / den2 + b[2 * HID + c]);
    float p = r0 * Wl[c] + r1 * Wl[HID + c] + r2 * Wl[2 * HID + c];
    int lane = c & 63, wv = c >> 6;
#pragma unroll
    for (int off = 32; off > 0; off >>= 1) p += __shfl_down(p, off);
    __shared__ float red[2];
    if (lane == 0) red[wv] = p;
    __syncthreads();
    if (c == 0) out[n] = 1.f / (1.f + __expf(-(red[0] + red[1] + bl[0])));
}

// ---------------- launch ----------------

extern "C" void kernel_launch(void* const* d_in, const int* in_sizes, int n_in,
                              void* d_out, int out_size, void* d_ws, size_t ws_size,
                              hipStream_t stream) {
    const float* z   = (const float*)d_in[0];
    const float* x   = (const float*)d_in[1];
    const int*   ei  = (const int*)d_in[2];
    const float* W1  = (const float*)d_in[3];
    const float* a1s = (const float*)d_in[4];
    const float* a1d = (const float*)d_in[5];
    const float* b1  = (const float*)d_in[6];
    const float* W2  = (const float*)d_in[7];
    const float* a2s = (const float*)d_in[8];
    const float* a2d = (const float*)d_in[9];
    const float* b2  = (const float*)d_in[10];
    const float* Wl  = (const float*)d_in[11];
    const float* bl  = (const float*)d_in[12];
    float* outp = (float*)d_out;

    int Nn = in_sizes[0] / 128;
    int E  = in_sizes[2] / 2;
    int Mpad = (Nn + 127) & ~127;

    char* p = (char*)d_ws;
    auto carve = [&](size_t bytes) -> char* {
        char* r = p;
        p += (bytes + 255) & ~(size_t)255;
        return r;
    };
    int*            offs   = (int*)carve((size_t)(Nn + 1) * 4);
    int*            cursor = (int*)carve((size_t)Nn * 4);
    int*            ssrc   = (int*)carve((size_t)E * 4);
    float*          e1s    = (float*)carve((size_t)Nn * 3 * 4);
    float*          e1d    = (float*)carve((size_t)Nn * 3 * 4);
    unsigned short* Abf    = (unsigned short*)carve((size_t)Mpad * 256 * 2);
    unsigned short* W1T    = (unsigned short*)carve((size_t)FDIM * 256 * 2);
    unsigned short* W2T    = (unsigned short*)carve((size_t)FDIM * 128 * 2);
    unsigned short* Hbf    = (unsigned short*)carve((size_t)Mpad * FDIM * 2);
    unsigned short* H2in   = (unsigned short*)carve((size_t)Mpad * 128 * 2);

    const int* srcI = ei;
    const int* dstI = ei + E;

    // CSR build
    hipMemsetAsync(cursor, 0, (size_t)Nn * 4, stream);
    k_hist<<<256, 256, 0, stream>>>(dstI, E, cursor);
    k_scan<<<1, 1024, 0, stream>>>(cursor, offs, Nn);
    k_copy<<<256, 256, 0, stream>>>(offs, cursor, Nn);
    k_scatter<<<256, 256, 0, stream>>>(srcI, dstI, E, cursor, ssrc);

    // bf16 converts
    k_cvt_concat<<<2048, 256, 0, stream>>>(z, x, Abf, Nn, Mpad);
    k_cvt_wt<<<FDIM, 256, 0, stream>>>(W1, W1T, 256, FDIM);
    k_cvt_wt<<<FDIM, 128, 0, stream>>>(W2, W2T, 128, FDIM);
    // zero pad rows of H2in (GEMM2 reads them)
    hipMemsetAsync(H2in + (size_t)Nn * 128, 0, (size_t)(Mpad - Nn) * 128 * 2, stream);

    dim3 gg(Mpad / 128, FDIM / 128);

    // Layer 1
    k_gemm_bf16<<<gg, 256, 0, stream>>>(Abf, W1T, Hbf, 256, FDIM);
    k_edge_logits<<<Nn, 128, 0, stream>>>(Hbf, a1s, a1d, e1s, e1d, Nn);
    k_gat_mean<<<Nn, 128, 0, stream>>>(Hbf, e1s, e1d, offs, ssrc, b1, H2in, Nn);

    // Layer 2 (+ fused linear + sigmoid)
    k_gemm_bf16<<<gg, 256, 0, stream>>>(H2in, W2T, Hbf, 128, FDIM);
    k_edge_logits<<<Nn, 128, 0, stream>>>(Hbf, a2s, a2d, e1s, e1d, Nn);
    k_gat_cat_final<<<Nn, 128, 0, stream>>>(Hbf, e1s, e1d, offs, ssrc, b2, Wl, bl, outp, Nn);
}

// Round 3
// 353.766 us; speedup vs baseline: 2.1050x; 1.2296x over previous
//
#include <hip/hip_runtime.h>
#include <stdint.h>

#define HEADS 3
#define HID 128
#define FDIM (HEADS * HID)   // 384

typedef __attribute__((ext_vector_type(8))) short bf16x8;
typedef __attribute__((ext_vector_type(4))) float f32x4;

__device__ __forceinline__ float lrelu(float x) { return x >= 0.f ? x : 0.2f * x; }
__device__ __forceinline__ float rrelu(float x) {
    const float SLOPE = (1.0f / 8.0f + 1.0f / 3.0f) * 0.5f;
    return x >= 0.f ? x : SLOPE * x;
}
__device__ __forceinline__ unsigned short f2bf(float f) {
    union { float f; unsigned u; } c; c.f = f;
    unsigned r = c.u + 0x7FFF + ((c.u >> 16) & 1);   // RNE
    return (unsigned short)(r >> 16);
}
__device__ __forceinline__ float bf2f(unsigned short b) {
    union { unsigned u; float f; } c; c.u = (unsigned)b << 16;
    return c.f;
}

__device__ __forceinline__ void gload_lds16(const void* g, void* l) {
    __builtin_amdgcn_global_load_lds(
        (const __attribute__((address_space(1))) void*)g,
        (__attribute__((address_space(3))) void*)l, 16, 0, 0);
}

// ---------------- CSR build (counting sort by dst) ----------------

__global__ void k_hist(const int* __restrict__ dst, int E, int* __restrict__ cnt) {
    for (int i = blockIdx.x * blockDim.x + threadIdx.x; i < E; i += gridDim.x * blockDim.x)
        atomicAdd(&cnt[dst[i]], 1);
}

// hierarchical scan: phase 1 — per-chunk exclusive scan + chunk totals
#define SC_T 256
#define SC_E 8
#define SC_CHUNK (SC_T * SC_E)   // 2048

__global__ __launch_bounds__(SC_T) void k_scan1(const int* __restrict__ cnt,
                                                int* __restrict__ exc,
                                                int* __restrict__ bsum, int n) {
    __shared__ int sm[SC_T];
    int b = blockIdx.x, t = threadIdx.x;
    int base = b * SC_CHUNK + t * SC_E;
    int v[SC_E];
    int s = 0;
#pragma unroll
    for (int i = 0; i < SC_E; i++) {
        int idx = base + i;
        v[i] = (idx < n) ? cnt[idx] : 0;
        s += v[i];
    }
    sm[t] = s;
    __syncthreads();
    for (int off = 1; off < SC_T; off <<= 1) {
        int x = (t >= off) ? sm[t - off] : 0;
        __syncthreads();
        sm[t] += x;
        __syncthreads();
    }
    int run = sm[t] - s;             // exclusive prefix of this thread's 8-group
    if (t == SC_T - 1) bsum[b] = sm[t];
#pragma unroll
    for (int i = 0; i < SC_E; i++) {
        int idx = base + i;
        if (idx < n) exc[idx] = run;
        run += v[i];
    }
}

// phase 2 — scan chunk totals (nb <= 256), write exclusive prefixes bpre[0..nb]
__global__ __launch_bounds__(256) void k_scan2(const int* __restrict__ bsum,
                                               int* __restrict__ bpre, int nb) {
    __shared__ int sm[256];
    int t = threadIdx.x;
    int v = (t < nb) ? bsum[t] : 0;
    sm[t] = v;
    __syncthreads();
    for (int off = 1; off < 256; off <<= 1) {
        int x = (t >= off) ? sm[t - off] : 0;
        __syncthreads();
        sm[t] += x;
        __syncthreads();
    }
    if (t < nb) bpre[t + 1] = sm[t];
    if (t == 0) bpre[0] = 0;
}

// phase 3 — add chunk prefix; produce offs and cursor copy
__global__ void k_scan3(int* __restrict__ offs, const int* __restrict__ bpre,
                        int* __restrict__ cursor, int n, int nb) {
    int i = blockIdx.x * blockDim.x + threadIdx.x;
    if (i < n) {
        int o = offs[i] + bpre[i / SC_CHUNK];
        offs[i] = o;
        cursor[i] = o;
    }
    if (i == 0) offs[n] = bpre[nb];
}

__global__ void k_scatter(const int* __restrict__ src, const int* __restrict__ dst, int E,
                          int* __restrict__ cursor, int* __restrict__ ssrc) {
    for (int i = blockIdx.x * blockDim.x + threadIdx.x; i < E; i += gridDim.x * blockDim.x) {
        int d = dst[i];
        int p = atomicAdd(&cursor[d], 1);
        ssrc[p] = src[i];
    }
}

// ---------------- bf16 converts ----------------

__global__ void k_cvt_concat(const float* __restrict__ z, const float* __restrict__ x,
                             unsigned short* __restrict__ A, int Nn, int Mpad) {
    int total = Mpad * 64;                       // 4 elems / thread
    for (int i = blockIdx.x * blockDim.x + threadIdx.x; i < total;
         i += gridDim.x * blockDim.x) {
        int row = i >> 6;
        int c4 = (i & 63) * 4;
        float4 v = make_float4(0.f, 0.f, 0.f, 0.f);
        if (row < Nn) {
            const float* sp = (c4 < 128) ? (z + (size_t)row * 128 + c4)
                                         : (x + (size_t)row * 128 + (c4 - 128));
            v = *(const float4*)sp;
        }
        unsigned short o[4] = {f2bf(v.x), f2bf(v.y), f2bf(v.z), f2bf(v.w)};
        *(uint2*)&A[(size_t)row * 256 + c4] = *(uint2*)o;
    }
}

__global__ void k_cvt_wt(const float* __restrict__ W, unsigned short* __restrict__ WT,
                         int K, int Ncols) {
    int n = blockIdx.x;
    for (int k = threadIdx.x; k < K; k += blockDim.x)
        WT[(size_t)n * K + k] = f2bf(W[(size_t)k * Ncols + n]);
}

// ---------------- bf16 MFMA GEMM ----------------

__global__ __launch_bounds__(256) void k_gemm_bf16(
    const unsigned short* __restrict__ A,
    const unsigned short* __restrict__ BT,
    unsigned short* __restrict__ C,
    int K, int Ncols) {
    __shared__ __align__(16) unsigned short As[128 * 32];
    __shared__ __align__(16) unsigned short Bs[128 * 32];
    int tid = threadIdx.x;
    int w = tid >> 6, lane = tid & 63;
    int row0 = blockIdx.x * 128;
    int col0 = blockIdx.y * 128;
    int wr = w >> 1, wc = w & 1;

    f32x4 acc[4][4] = {};
    int frow = lane & 15;
    int fk = (lane >> 4) * 8;

    for (int k0 = 0; k0 < K; k0 += 32) {
#pragma unroll
        for (int i = 0; i < 2; i++) {
            int c = (i * 4 + w) * 64 + lane;
            gload_lds16(A + (size_t)(row0 + (c >> 2)) * K + k0 + (c & 3) * 8,
                        (char*)As + (i * 4 + w) * 1024);
        }
#pragma unroll
        for (int i = 0; i < 2; i++) {
            int c = (i * 4 + w) * 64 + lane;
            gload_lds16(BT + (size_t)(col0 + (c >> 2)) * K + k0 + (c & 3) * 8,
                        (char*)Bs + (i * 4 + w) * 1024);
        }
        asm volatile("s_waitcnt vmcnt(0)" ::: "memory");
        __syncthreads();

        bf16x8 af[4], bfr[4];
#pragma unroll
        for (int m = 0; m < 4; m++)
            af[m] = *(const bf16x8*)&As[(wr * 64 + m * 16 + frow) * 32 + fk];
#pragma unroll
        for (int n = 0; n < 4; n++)
            bfr[n] = *(const bf16x8*)&Bs[(wc * 64 + n * 16 + frow) * 32 + fk];
#pragma unroll
        for (int m = 0; m < 4; m++)
#pragma unroll
            for (int n = 0; n < 4; n++)
                acc[m][n] = __builtin_amdgcn_mfma_f32_16x16x32_bf16(af[m], bfr[n], acc[m][n], 0, 0, 0);
        __syncthreads();
    }

    int ccol = lane & 15, crow = (lane >> 4) * 4;
#pragma unroll
    for (int m = 0; m < 4; m++)
#pragma unroll
        for (int n = 0; n < 4; n++)
#pragma unroll
            for (int j = 0; j < 4; j++) {
                int r = row0 + wr * 64 + m * 16 + crow + j;
                int cc = col0 + wc * 64 + n * 16 + ccol;
                C[(size_t)r * Ncols + cc] = f2bf(acc[m][n][j]);
            }
}

// ---------------- per-node attention logits ----------------

__global__ __launch_bounds__(128) void k_edge_logits(const unsigned short* __restrict__ H,
                                                     const float* __restrict__ asrc,
                                                     const float* __restrict__ adst,
                                                     float* __restrict__ es,
                                                     float* __restrict__ ed, int Nn) {
    int n = blockIdx.x;
    int t = threadIdx.x;
    int lane = t & 63, wv = t >> 6;
    __shared__ float red[2][HEADS][2];
#pragma unroll
    for (int h = 0; h < HEADS; h++) {
        float v = bf2f(H[(size_t)n * FDIM + h * HID + t]);
        float ps = v * asrc[h * HID + t];
        float pd = v * adst[h * HID + t];
#pragma unroll
        for (int off = 32; off > 0; off >>= 1) {
            ps += __shfl_down(ps, off);
            pd += __shfl_down(pd, off);
        }
        if (lane == 0) { red[wv][h][0] = ps; red[wv][h][1] = pd; }
    }
    __syncthreads();
    if (t < HEADS) {
        es[n * HEADS + t] = red[0][t][0] + red[1][t][0];
        ed[n * HEADS + t] = red[0][t][1] + red[1][t][1];
    }
}

// ---------------- GAT aggregate, layer 1 ----------------

__global__ __launch_bounds__(128) void k_gat_mean(const unsigned short* __restrict__ H,
                                                  const float* __restrict__ es,
                                                  const float* __restrict__ ed,
                                                  const int* __restrict__ offs,
                                                  const int* __restrict__ ssrc,
                                                  const float* __restrict__ b,
                                                  unsigned short* __restrict__ out, int Nn) {
    int n = blockIdx.x;
    int c = threadIdx.x;
    float ed0 = ed[n * 3 + 0], ed1 = ed[n * 3 + 1], ed2 = ed[n * 3 + 2];
    float acc0 = 0, acc1 = 0, acc2 = 0, den0 = 0, den1 = 0, den2 = 0;
    int j0 = offs[n], j1 = offs[n + 1];
    for (int j = j0 - 1; j < j1; j++) {          // j0-1 == self loop
        int s = (j < j0) ? n : ssrc[j];
        float w0 = __expf(lrelu(es[s * 3 + 0] + ed0));
        float w1 = __expf(lrelu(es[s * 3 + 1] + ed1));
        float w2 = __expf(lrelu(es[s * 3 + 2] + ed2));
        const unsigned short* hp = H + (size_t)s * FDIM + c;
        acc0 = fmaf(w0, bf2f(hp[0]), acc0);
        acc1 = fmaf(w1, bf2f(hp[HID]), acc1);
        acc2 = fmaf(w2, bf2f(hp[2 * HID]), acc2);
        den0 += w0; den1 += w1; den2 += w2;
    }
    float m = (acc0 / den0 + acc1 / den1 + acc2 / den2) * (1.f / 3.f) + b[c];
    out[(size_t)n * HID + c] = f2bf(rrelu(m));
}

// ---------------- GAT aggregate, layer 2 + linear + sigmoid ----------------

__global__ __launch_bounds__(128) void k_gat_cat_final(const unsigned short* __restrict__ H,
                                                       const float* __restrict__ es,
                                                       const float* __restrict__ ed,
                                                       const int* __restrict__ offs,
                                                       const int* __restrict__ ssrc,
                                                       const float* __restrict__ b,
                                                       const float* __restrict__ Wl,
                                                       const float* __restrict__ bl,
                                                       float* __restrict__ out, int Nn) {
    int n = blockIdx.x;
    int c = threadIdx.x;
    float ed0 = ed[n * 3 + 0], ed1 = ed[n * 3 + 1], ed2 = ed[n * 3 + 2];
    float acc0 = 0, acc1 = 0, acc2 = 0, den0 = 0, den1 = 0, den2 = 0;
    int j0 = offs[n], j1 = offs[n + 1];
    for (int j = j0 - 1; j < j1; j++) {
        int s = (j < j0) ? n : ssrc[j];
        float w0 = __expf(lrelu(es[s * 3 + 0] + ed0));
        float w1 = __expf(lrelu(es[s * 3 + 1] + ed1));
        float w2 = __expf(lrelu(es[s * 3 + 2] + ed2));
        const unsigned short* hp = H + (size_t)s * FDIM + c;
        acc0 = fmaf(w0, bf2f(hp[0]), acc0);
        acc1 = fmaf(w1, bf2f(hp[HID]), acc1);
        acc2 = fmaf(w2, bf2f(hp[2 * HID]), acc2);
        den0 += w0; den1 += w1; den2 += w2;
    }
    float r0 = rrelu(acc0 / den0 + b[c]);
    float r1 = rrelu(acc1 / den1 + b[HID + c]);
    float r2 = rrelu(acc2 / den2 + b[2 * HID + c]);
    float p = r0 * Wl[c] + r1 * Wl[HID + c] + r2 * Wl[2 * HID + c];
    int lane = c & 63, wv = c >> 6;
#pragma unroll
    for (int off = 32; off > 0; off >>= 1) p += __shfl_down(p, off);
    __shared__ float red[2];
    if (lane == 0) red[wv] = p;
    __syncthreads();
    if (c == 0) out[n] = 1.f / (1.f + __expf(-(red[0] + red[1] + bl[0])));
}

// ---------------- launch ----------------

extern "C" void kernel_launch(void* const* d_in, const int* in_sizes, int n_in,
                              void* d_out, int out_size, void* d_ws, size_t ws_size,
                              hipStream_t stream) {
    const float* z   = (const float*)d_in[0];
    const float* x   = (const float*)d_in[1];
    const int*   ei  = (const int*)d_in[2];
    const float* W1  = (const float*)d_in[3];
    const float* a1s = (const float*)d_in[4];
    const float* a1d = (const float*)d_in[5];
    const float* b1  = (const float*)d_in[6];
    const float* W2  = (const float*)d_in[7];
    const float* a2s = (const float*)d_in[8];
    const float* a2d = (const float*)d_in[9];
    const float* b2  = (const float*)d_in[10];
    const float* Wl  = (const float*)d_in[11];
    const float* bl  = (const float*)d_in[12];
    float* outp = (float*)d_out;

    int Nn = in_sizes[0] / 128;
    int E  = in_sizes[2] / 2;
    int Mpad = (Nn + 127) & ~127;
    int nb = (Nn + SC_CHUNK - 1) / SC_CHUNK;

    char* p = (char*)d_ws;
    auto carve = [&](size_t bytes) -> char* {
        char* r = p;
        p += (bytes + 255) & ~(size_t)255;
        return r;
    };
    int*            offs   = (int*)carve((size_t)(Nn + 1) * 4);
    int*            cursor = (int*)carve((size_t)Nn * 4);
    int*            ssrc   = (int*)carve((size_t)E * 4);
    int*            bsum   = (int*)carve((size_t)(nb + 1) * 4);
    int*            bpre   = (int*)carve((size_t)(nb + 1) * 4);
    float*          e1s    = (float*)carve((size_t)Nn * 3 * 4);
    float*          e1d    = (float*)carve((size_t)Nn * 3 * 4);
    unsigned short* Abf    = (unsigned short*)carve((size_t)Mpad * 256 * 2);
    unsigned short* W1T    = (unsigned short*)carve((size_t)FDIM * 256 * 2);
    unsigned short* W2T    = (unsigned short*)carve((size_t)FDIM * 128 * 2);
    unsigned short* Hbf    = (unsigned short*)carve((size_t)Mpad * FDIM * 2);
    unsigned short* H2in   = (unsigned short*)carve((size_t)Mpad * 128 * 2);

    const int* srcI = ei;
    const int* dstI = ei + E;

    // CSR build (hierarchical scan)
    hipMemsetAsync(cursor, 0, (size_t)Nn * 4, stream);
    k_hist<<<256, 256, 0, stream>>>(dstI, E, cursor);
    k_scan1<<<nb, SC_T, 0, stream>>>(cursor, offs, bsum, Nn);
    k_scan2<<<1, 256, 0, stream>>>(bsum, bpre, nb);
    k_scan3<<<(Nn + 255) / 256, 256, 0, stream>>>(offs, bpre, cursor, Nn, nb);
    k_scatter<<<256, 256, 0, stream>>>(srcI, dstI, E, cursor, ssrc);

    // bf16 converts
    k_cvt_concat<<<2048, 256, 0, stream>>>(z, x, Abf, Nn, Mpad);
    k_cvt_wt<<<FDIM, 256, 0, stream>>>(W1, W1T, 256, FDIM);
    k_cvt_wt<<<FDIM, 128, 0, stream>>>(W2, W2T, 128, FDIM);
    hipMemsetAsync(H2in + (size_t)Nn * 128, 0, (size_t)(Mpad - Nn) * 128 * 2, stream);

    dim3 gg(Mpad / 128, FDIM / 128);

    // Layer 1
    k_gemm_bf16<<<gg, 256, 0, stream>>>(Abf, W1T, Hbf, 256, FDIM);
    k_edge_logits<<<Nn, 128, 0, stream>>>(Hbf, a1s, a1d, e1s, e1d, Nn);
    k_gat_mean<<<Nn, 128, 0, stream>>>(Hbf, e1s, e1d, offs, ssrc, b1, H2in, Nn);

    // Layer 2 (+ fused linear + sigmoid)
    k_gemm_bf16<<<gg, 256, 0, stream>>>(H2in, W2T, Hbf, 128, FDIM);
    k_edge_logits<<<Nn, 128, 0, stream>>>(Hbf, a2s, a2d, e1s, e1d, Nn);
    k_gat_cat_final<<<Nn, 128, 0, stream>>>(Hbf, e1s, e1d, offs, ssrc, b2, Wl, bl, outp, Nn);
}